// Round 6
// baseline (138.618 us; speedup 1.0000x reference)
//
#include <hip/hip_runtime.h>

#define IN_DIM 128
#define CAP 64          // per-node bucket capacity; dataset max degree ~ 1+Poisson(15) << 64
#define NODE_SHIFT 8    // 256 nodes per coarse bin
#define BIN_NODES (1 << NODE_SHIFT)
#define NB_MAX 512      // supports n_n up to 131072
#define BCAP 6144       // pairs per bin; expected ~4092 +- ~64, ~32 sigma slack
#define CHUNK 2048      // edges per partition block (16KB LDS staging)

typedef __attribute__((ext_vector_type(8))) short bf16x8;
typedef __attribute__((ext_vector_type(4))) float f32x4;
typedef __attribute__((ext_vector_type(2))) float f32x2;

__device__ __forceinline__ unsigned short f2bf(float f) {
    unsigned int u = __float_as_uint(f);
    u += 0x7FFFu + ((u >> 16) & 1u);   // round-to-nearest-even
    return (unsigned short)(u >> 16);
}

__global__ void k_zero(int* __restrict__ p, int n) {
    int i = blockIdx.x * blockDim.x + threadIdx.x;
    if (i < n) p[i] = 0;
}

// Pass 1: partition edges into coarse bins of 256 head-nodes each.
__global__ __launch_bounds__(256) void k_partition(const int* __restrict__ edges, int n_e,
                                                   int nbins,
                                                   unsigned long long* __restrict__ pairs,
                                                   int* __restrict__ bincur) {
    __shared__ unsigned long long sp[CHUNK];   // 16 KB staged (h,t) pairs
    __shared__ int hist[NB_MAX];
    __shared__ int base[NB_MAX];
    int tid = threadIdx.x;
    int e0 = blockIdx.x * CHUNK;
    int nloc = n_e - e0;
    if (nloc > CHUNK) nloc = CHUNK;
    for (int i = tid; i < nbins; i += 256) hist[i] = 0;
    __syncthreads();
    for (int i = tid; i < nloc; i += 256) {
        int h = edges[e0 + i];
        int t = edges[n_e + e0 + i];
        sp[i] = ((unsigned long long)(unsigned int)h << 32) | (unsigned int)t;
        atomicAdd(&hist[h >> NODE_SHIFT], 1);
    }
    __syncthreads();
    for (int b = tid; b < nbins; b += 256) {
        int c = hist[b];
        base[b] = c ? atomicAdd(&bincur[b], c) : 0;
        hist[b] = 0;
    }
    __syncthreads();
    for (int i = tid; i < nloc; i += 256) {
        unsigned long long p = sp[i];
        int b = (int)(p >> (32 + NODE_SHIFT));
        int pos = atomicAdd(&hist[b], 1);
        int g = base[b] + pos;
        if (g < BCAP) pairs[(size_t)b * BCAP + g] = p;
    }
}

// Pass 2: one block per bin; per-node cursors in LDS; emits degree + rsd.
// Bucket tail slots (d .. pad16(d)) are filled with the dummy row index n_n
// so k_agg's hot loop needs no masking.
__global__ __launch_bounds__(256) void k_binscatter(const unsigned long long* __restrict__ pairs,
                                                    const int* __restrict__ bincur,
                                                    int* __restrict__ bucket,
                                                    int* __restrict__ cursor,
                                                    float* __restrict__ rsd, int n_n) {
    __shared__ int lcur[BIN_NODES];
    int b = blockIdx.x;
    int tid = threadIdx.x;
    for (int i = tid; i < BIN_NODES; i += 256) lcur[i] = 0;
    __syncthreads();
    int n = bincur[b];
    if (n > BCAP) n = BCAP;
    const unsigned long long* pp = pairs + (size_t)b * BCAP;
    int h0 = b << NODE_SHIFT;
    for (int i = tid; i < n; i += 256) {
        unsigned long long p = pp[i];
        int h = (int)(p >> 32);
        int t = (int)(p & 0xffffffffu);
        int pos = atomicAdd(&lcur[h - h0], 1);
        if (pos < CAP) bucket[(size_t)h * CAP + pos] = t;
    }
    __syncthreads();
    for (int i = tid; i < BIN_NODES; i += 256) {
        int h = h0 + i;
        if (h < n_n) {
            int d = lcur[i];
            if (d > CAP) d = CAP;
            cursor[h] = d;
            rsd[h] = d > 0 ? rsqrtf((float)d) : 0.0f;
            int dpad = (d + 15) & ~15;
            for (int s = d; s < dpad; ++s) bucket[(size_t)h * CAP + s] = n_n;
        }
    }
}

// Convert W (128x128 fp32, row-major, dot along k) to bf16 in a swizzled
// 16B-granule layout: granule (n, g) -> Wsw[n*16 + (g ^ (n&7))].
__global__ void k_wconv(const float* __restrict__ W, bf16x8* __restrict__ Wsw) {
    int gi = blockIdx.x * 256 + threadIdx.x;
    if (gi >= 2048) return;
    int n = gi >> 4, g = gi & 15;
    const float* wp = W + n * IN_DIM + g * 8;
    float4 a = *(const float4*)wp;
    float4 b = *(const float4*)(wp + 4);
    bf16x8 v;
    v[0] = (short)f2bf(a.x); v[1] = (short)f2bf(a.y);
    v[2] = (short)f2bf(a.z); v[3] = (short)f2bf(a.w);
    v[4] = (short)f2bf(b.x); v[5] = (short)f2bf(b.y);
    v[6] = (short)f2bf(b.z); v[7] = (short)f2bf(b.w);
    Wsw[n * 16 + (g ^ (n & 7))] = v;
}

// Y2[m, :] = bf16( rsd[m] * (X[m, :] @ W^T) ) via bf16 MFMA, fp32 accumulate.
__global__ __launch_bounds__(256) void k_mfma(const float* __restrict__ X,
                                              const bf16x8* __restrict__ Wg,
                                              const float* __restrict__ rsd,
                                              unsigned short* __restrict__ Y2, int M) {
    __shared__ bf16x8 WL[2048];   // 32 KB swizzled bf16 W
    int tid = threadIdx.x;
    for (int i = tid; i < 2048; i += 256) WL[i] = Wg[i];
    __syncthreads();
    int slab = blockIdx.x * 4 + (tid >> 6);
    int m0 = slab * 16;
    if (m0 >= M) return;
    int l = tid & 63;
    int lm = l & 15, lk = l >> 4;
    int row = m0 + lm;
    int rowc = row < M ? row : M - 1;
    bf16x8 xf[4];
    const float* xbase = X + (size_t)rowc * IN_DIM + lk * 8;
    #pragma unroll
    for (int ks = 0; ks < 4; ++ks) {
        float4 a = *(const float4*)(xbase + ks * 32);
        float4 b = *(const float4*)(xbase + ks * 32 + 4);
        bf16x8 v;
        v[0] = (short)f2bf(a.x); v[1] = (short)f2bf(a.y);
        v[2] = (short)f2bf(a.z); v[3] = (short)f2bf(a.w);
        v[4] = (short)f2bf(b.x); v[5] = (short)f2bf(b.y);
        v[6] = (short)f2bf(b.z); v[7] = (short)f2bf(b.w);
        xf[ks] = v;
    }
    float s = rsd[rowc];
    #pragma unroll
    for (int nt = 0; nt < 8; ++nt) {
        f32x4 acc = {0.f, 0.f, 0.f, 0.f};
        #pragma unroll
        for (int ks = 0; ks < 4; ++ks) {
            int n = nt * 16 + lm;
            int g = ks * 4 + lk;
            bf16x8 wf = WL[n * 16 + (g ^ (n & 7))];
            acc = __builtin_amdgcn_mfma_f32_16x16x32_bf16(wf, xf[ks], acc, 0, 0, 0);
        }
        if (row < M) {
            unsigned int lo = (unsigned int)f2bf(acc[0] * s) |
                              ((unsigned int)f2bf(acc[1] * s) << 16);
            unsigned int hi = (unsigned int)f2bf(acc[2] * s) |
                              ((unsigned int)f2bf(acc[3] * s) << 16);
            uint2* yp = (uint2*)(Y2 + (size_t)row * IN_DIM + nt * 16 + lk * 4);
            *yp = make_uint2(lo, hi);
        }
    }
}

// Persistent waves, 1-deep software pipeline over nodes. Lane l: dims 8a..8a+7
// (a=l&15), edge sub-slot grp=l>>4. Next node's cursor + first 32 edge targets
// are loaded while the current node's 256B-row gathers are in flight, removing
// the per-node dependent prologue chain. Bucket tails pre-padded with dummy
// row index n_n -> no masking in hot loop. rsd recomputed as rsqrt(d).
__global__ __launch_bounds__(256) void k_agg(const uint4* __restrict__ Y4,
                                             const int* __restrict__ bucket,
                                             const int* __restrict__ cursor,
                                             float* __restrict__ out, int n_n) {
    int wid = (int)((blockIdx.x * 256u + threadIdx.x) >> 6);
    int nw = (int)(gridDim.x * 4u);     // total waves
    int lane = threadIdx.x & 63;
    int grp = lane >> 4, a = lane & 15;
    const uint4* bk = (const uint4*)bucket;   // 16 uint4 per node row

    int gw = wid;
    if (gw >= n_n) return;
    int d_cur = cursor[gw];
    uint4 tv0 = bk[(size_t)gw * 16 + grp];
    uint4 tv1 = bk[(size_t)gw * 16 + 4 + grp];

    #define ACCUM(V)                                                          \
    {                                                                         \
        f32x2 x;                                                              \
        x[0] = __uint_as_float((V).x << 16);                                  \
        x[1] = __uint_as_float((V).x & 0xffff0000u);                          \
        asm("v_pk_add_f32 %0, %1, %0" : "+v"(a0) : "v"(x));                   \
        x[0] = __uint_as_float((V).y << 16);                                  \
        x[1] = __uint_as_float((V).y & 0xffff0000u);                          \
        asm("v_pk_add_f32 %0, %1, %0" : "+v"(a1) : "v"(x));                   \
        x[0] = __uint_as_float((V).z << 16);                                  \
        x[1] = __uint_as_float((V).z & 0xffff0000u);                          \
        asm("v_pk_add_f32 %0, %1, %0" : "+v"(a2) : "v"(x));                   \
        x[0] = __uint_as_float((V).w << 16);                                  \
        x[1] = __uint_as_float((V).w & 0xffff0000u);                          \
        asm("v_pk_add_f32 %0, %1, %0" : "+v"(a3) : "v"(x));                   \
    }

    while (gw < n_n) {
        // ---- prefetch next node's state (hidden under this node's gathers)
        int gn = gw + nw;
        int d_nxt = 0;
        uint4 nv0 = make_uint4(0, 0, 0, 0), nv1 = make_uint4(0, 0, 0, 0);
        if (gn < n_n) {
            d_nxt = cursor[gn];
            nv0 = bk[(size_t)gn * 16 + grp];
            nv1 = bk[(size_t)gn * 16 + 4 + grp];
        }
        // ---- gather + accumulate current node
        f32x2 a0 = {0.f, 0.f}, a1 = {0.f, 0.f}, a2 = {0.f, 0.f}, a3 = {0.f, 0.f};
        {
            uint4 v0 = Y4[(size_t)tv0.x * 16 + a];
            uint4 v1 = Y4[(size_t)tv0.y * 16 + a];
            uint4 v2 = Y4[(size_t)tv0.z * 16 + a];
            uint4 v3 = Y4[(size_t)tv0.w * 16 + a];
            ACCUM(v0) ACCUM(v1) ACCUM(v2) ACCUM(v3)
        }
        if (d_cur > 16) {
            uint4 v0 = Y4[(size_t)tv1.x * 16 + a];
            uint4 v1 = Y4[(size_t)tv1.y * 16 + a];
            uint4 v2 = Y4[(size_t)tv1.z * 16 + a];
            uint4 v3 = Y4[(size_t)tv1.w * 16 + a];
            ACCUM(v0) ACCUM(v1) ACCUM(v2) ACCUM(v3)
        }
        for (int b = 2; b * 16 < d_cur; ++b) {   // d>32: rare (~3 nodes)
            uint4 tv = bk[(size_t)gw * 16 + b * 4 + grp];
            uint4 v0 = Y4[(size_t)tv.x * 16 + a];
            uint4 v1 = Y4[(size_t)tv.y * 16 + a];
            uint4 v2 = Y4[(size_t)tv.z * 16 + a];
            uint4 v3 = Y4[(size_t)tv.w * 16 + a];
            ACCUM(v0) ACCUM(v1) ACCUM(v2) ACCUM(v3)
        }
        // ---- merge the 4 edge sub-slot groups (lanes a, a+16, a+32, a+48)
        a0[0] += __shfl_xor(a0[0], 16); a0[1] += __shfl_xor(a0[1], 16);
        a0[0] += __shfl_xor(a0[0], 32); a0[1] += __shfl_xor(a0[1], 32);
        a1[0] += __shfl_xor(a1[0], 16); a1[1] += __shfl_xor(a1[1], 16);
        a1[0] += __shfl_xor(a1[0], 32); a1[1] += __shfl_xor(a1[1], 32);
        a2[0] += __shfl_xor(a2[0], 16); a2[1] += __shfl_xor(a2[1], 16);
        a2[0] += __shfl_xor(a2[0], 32); a2[1] += __shfl_xor(a2[1], 32);
        a3[0] += __shfl_xor(a3[0], 16); a3[1] += __shfl_xor(a3[1], 16);
        a3[0] += __shfl_xor(a3[0], 32); a3[1] += __shfl_xor(a3[1], 32);
        if (lane < 16) {
            float s = rsqrtf((float)d_cur);
            float4 o0 = make_float4(fmaxf(a0[0] * s, 0.f), fmaxf(a0[1] * s, 0.f),
                                    fmaxf(a1[0] * s, 0.f), fmaxf(a1[1] * s, 0.f));
            float4 o1 = make_float4(fmaxf(a2[0] * s, 0.f), fmaxf(a2[1] * s, 0.f),
                                    fmaxf(a3[0] * s, 0.f), fmaxf(a3[1] * s, 0.f));
            float4* op = (float4*)(out + (size_t)gw * IN_DIM + a * 8);
            op[0] = o0;
            op[1] = o1;
        }
        gw = gn; d_cur = d_nxt; tv0 = nv0; tv1 = nv1;
    }
    #undef ACCUM
}

extern "C" void kernel_launch(void* const* d_in, const int* in_sizes, int n_in,
                              void* d_out, int out_size, void* d_ws, size_t ws_size,
                              hipStream_t stream) {
    const float* X = (const float*)d_in[0];
    const int* edges = (const int*)d_in[1];
    const float* W = (const float*)d_in[2];
    int n_n = in_sizes[0] / IN_DIM;
    int n_e = in_sizes[1] / 2;
    int nbins = (n_n + BIN_NODES - 1) >> NODE_SHIFT;   // 391 for n_n=100000

    char* ws = (char*)d_ws;
    size_t o = 0;
    auto take = [&](size_t bytes) -> char* {
        char* p = ws + o;
        o += (bytes + 511) & ~(size_t)511;
        return p;
    };
    int* cursor = (int*)take((size_t)n_n * 4);                        // 400 KB
    float* rsd = (float*)take((size_t)n_n * 4);                       // 400 KB
    int* bucket = (int*)take((size_t)n_n * CAP * 4);                  // 25.6 MB
    // pairs (19.2 MB) aliases Y2's slot: consumed by k_binscatter before
    // k_mfma writes Y2. Y2 has n_n+1 rows; row n_n is the zeroed dummy row.
    size_t y2_bytes = (size_t)(n_n + 1) * IN_DIM * 2;                 // 25.6 MB
    size_t pair_bytes = (size_t)nbins * BCAP * 8;                     // 19.2 MB
    char* big = take(y2_bytes > pair_bytes ? y2_bytes : pair_bytes);
    unsigned short* Y2 = (unsigned short*)big;
    unsigned long long* pairs = (unsigned long long*)big;
    int* bincur = (int*)take((size_t)nbins * 4);
    bf16x8* Wsw = (bf16x8*)take(2048 * 16);                           // 32 KB

    int nslab = (n_n + 15) / 16;
    k_zero<<<(nbins + 255) / 256, 256, 0, stream>>>(bincur, nbins);
    k_zero<<<1, 256, 0, stream>>>((int*)(Y2 + (size_t)n_n * IN_DIM), IN_DIM / 2);
    k_partition<<<(n_e + CHUNK - 1) / CHUNK, 256, 0, stream>>>(edges, n_e, nbins, pairs, bincur);
    k_wconv<<<8, 256, 0, stream>>>(W, Wsw);
    k_binscatter<<<nbins, 256, 0, stream>>>(pairs, bincur, bucket, cursor, rsd, n_n);
    k_mfma<<<(nslab + 3) / 4, 256, 0, stream>>>(X, Wsw, rsd, Y2, n_n);
    int nblk = (n_n + 3) / 4;
    if (nblk > 2048) nblk = 2048;       // persistent waves, full residency
    k_agg<<<nblk, 256, 0, stream>>>((const uint4*)Y2, bucket, cursor,
                                    (float*)d_out, n_n);
}

// Round 7
// 127.229 us; speedup vs baseline: 1.0895x; 1.0895x over previous
//
#include <hip/hip_runtime.h>

#define IN_DIM 128
#define CAP 64          // per-node degree cap; dataset max degree ~ 1+Poisson(15) << 64
#define NODE_SHIFT 8    // 256 nodes per coarse bin
#define BIN_NODES 256   // == blockDim of k_binscatter
#define NB_MAX 512      // supports n_n up to 131072
#define BCAP 6144       // pairs per bin; mean ~4096, sigma ~64 -> 32 sigma slack
#define BINCAP_E 10240  // bucket entries per bin (padded CSR region), mean ~6000
#define CHUNK 4096      // edges per partition block (32KB LDS staging)

typedef __attribute__((ext_vector_type(8))) short bf16x8;
typedef __attribute__((ext_vector_type(4))) float f32x4;
typedef __attribute__((ext_vector_type(2))) float f32x2;

__device__ __forceinline__ unsigned short f2bf(float f) {
    unsigned int u = __float_as_uint(f);
    u += 0x7FFFu + ((u >> 16) & 1u);   // round-to-nearest-even
    return (unsigned short)(u >> 16);
}

// Fused prep: zero bincur, zero dummy Y2 row, convert W to swizzled bf16
// granules: (n, g) -> Wsw[n*16 + (g ^ (n&7))].
__global__ void k_prep(const float* __restrict__ W, bf16x8* __restrict__ Wsw,
                       int* __restrict__ bincur, int nbins,
                       unsigned int* __restrict__ dummy) {
    int gi = blockIdx.x * 256 + threadIdx.x;
    if (gi < nbins) bincur[gi] = 0;
    if (gi < 64) dummy[gi] = 0;
    if (gi >= 2048) return;
    int n = gi >> 4, g = gi & 15;
    const float* wp = W + n * IN_DIM + g * 8;
    float4 a = *(const float4*)wp;
    float4 b = *(const float4*)(wp + 4);
    bf16x8 v;
    v[0] = (short)f2bf(a.x); v[1] = (short)f2bf(a.y);
    v[2] = (short)f2bf(a.z); v[3] = (short)f2bf(a.w);
    v[4] = (short)f2bf(b.x); v[5] = (short)f2bf(b.y);
    v[6] = (short)f2bf(b.z); v[7] = (short)f2bf(b.w);
    Wsw[n * 16 + (g ^ (n & 7))] = v;
}

// Pass 1: partition edges into coarse bins of 256 head-nodes each.
__global__ __launch_bounds__(256) void k_partition(const int* __restrict__ edges, int n_e,
                                                   int nbins,
                                                   unsigned long long* __restrict__ pairs,
                                                   int* __restrict__ bincur) {
    __shared__ unsigned long long sp[CHUNK];   // 32 KB staged (h,t) pairs
    __shared__ int hist[NB_MAX];
    __shared__ int base[NB_MAX];
    int tid = threadIdx.x;
    int e0 = blockIdx.x * CHUNK;
    int nloc = n_e - e0;
    if (nloc > CHUNK) nloc = CHUNK;
    for (int i = tid; i < nbins; i += 256) hist[i] = 0;
    __syncthreads();
    for (int i = tid; i < nloc; i += 256) {
        int h = edges[e0 + i];
        int t = edges[n_e + e0 + i];
        sp[i] = ((unsigned long long)(unsigned int)h << 32) | (unsigned int)t;
        atomicAdd(&hist[h >> NODE_SHIFT], 1);
    }
    __syncthreads();
    for (int b = tid; b < nbins; b += 256) {
        int c = hist[b];
        base[b] = c ? atomicAdd(&bincur[b], c) : 0;
        hist[b] = 0;
    }
    __syncthreads();
    for (int i = tid; i < nloc; i += 256) {
        unsigned long long p = sp[i];
        int b = (int)(p >> (32 + NODE_SHIFT));
        int pos = atomicAdd(&hist[b], 1);
        int g = base[b] + pos;
        if (g < BCAP) pairs[(size_t)b * BCAP + g] = p;
    }
}

// Pass 2: one block (256 thr) per bin; thread i owns node h0+i. Count pass ->
// exclusive scan of pad16(deg) -> compact padded-CSR scatter into the bin's
// fixed BINCAP_E region. Emits rowinfo=(global base, capped deg) and rsd.
// Tail slots padded with dummy row index n_n -> k_agg hot loop is mask-free.
__global__ __launch_bounds__(256) void k_binscatter(const unsigned long long* __restrict__ pairs,
                                                    const int* __restrict__ bincur,
                                                    int* __restrict__ bucket,
                                                    int2* __restrict__ rowinfo,
                                                    float* __restrict__ rsd, int n_n) {
    __shared__ int lcur[BIN_NODES];
    __shared__ int sbase[BIN_NODES];
    __shared__ int wsum[4];
    int b = blockIdx.x;
    int tid = threadIdx.x;
    lcur[tid] = 0;
    __syncthreads();
    int n = bincur[b];
    if (n > BCAP) n = BCAP;
    const unsigned long long* pp = pairs + (size_t)b * BCAP;
    int h0 = b << NODE_SHIFT;
    for (int i = tid; i < n; i += 256) {
        int h = (int)(pp[i] >> 32);
        atomicAdd(&lcur[h - h0], 1);
    }
    __syncthreads();
    int draw = lcur[tid];
    int dcap = draw < CAP ? draw : CAP;
    int v = (dcap + 15) & ~15;          // padded degree (multiple of 16)
    // exclusive scan of v over the 256 threads (4 waves)
    int lane = tid & 63, w = tid >> 6;
    int x = v;
    #pragma unroll
    for (int off = 1; off < 64; off <<= 1) {
        int y = __shfl_up(x, off);
        if (lane >= off) x += y;
    }
    if (lane == 63) wsum[w] = x;
    __syncthreads();
    int wo = 0;
    for (int k = 0; k < w; ++k) wo += wsum[k];
    int base = wo + x - v;              // intra-bin exclusive prefix
    sbase[tid] = base;
    lcur[tid] = 0;
    __syncthreads();
    int gbase = b * BINCAP_E;
    for (int i = tid; i < n; i += 256) {
        unsigned long long p = pp[i];
        int h = (int)(p >> 32);
        int t = (int)(p & 0xffffffffu);
        int li = h - h0;
        int pos = atomicAdd(&lcur[li], 1);
        if (pos < CAP) {
            int idx = sbase[li] + pos;
            if (idx < BINCAP_E) bucket[gbase + idx] = t;
        }
    }
    __syncthreads();
    int h = h0 + tid;
    if (h < n_n) {
        for (int s = dcap; s < v; ++s) {
            int idx = base + s;
            if (idx < BINCAP_E) bucket[gbase + idx] = n_n;
        }
        rowinfo[h] = make_int2(gbase + base, dcap);
        rsd[h] = draw > 0 ? rsqrtf((float)draw) : 0.0f;
    }
}

// Y2[m, :] = bf16( rsd[m] * (X[m, :] @ W^T) ) via bf16 MFMA, fp32 accumulate.
__global__ __launch_bounds__(256) void k_mfma(const float* __restrict__ X,
                                              const bf16x8* __restrict__ Wg,
                                              const float* __restrict__ rsd,
                                              unsigned short* __restrict__ Y2, int M) {
    __shared__ bf16x8 WL[2048];   // 32 KB swizzled bf16 W
    int tid = threadIdx.x;
    for (int i = tid; i < 2048; i += 256) WL[i] = Wg[i];
    __syncthreads();
    int slab = blockIdx.x * 4 + (tid >> 6);
    int m0 = slab * 16;
    if (m0 >= M) return;
    int l = tid & 63;
    int lm = l & 15, lk = l >> 4;
    int row = m0 + lm;
    int rowc = row < M ? row : M - 1;
    bf16x8 xf[4];
    const float* xbase = X + (size_t)rowc * IN_DIM + lk * 8;
    #pragma unroll
    for (int ks = 0; ks < 4; ++ks) {
        float4 a = *(const float4*)(xbase + ks * 32);
        float4 b = *(const float4*)(xbase + ks * 32 + 4);
        bf16x8 v;
        v[0] = (short)f2bf(a.x); v[1] = (short)f2bf(a.y);
        v[2] = (short)f2bf(a.z); v[3] = (short)f2bf(a.w);
        v[4] = (short)f2bf(b.x); v[5] = (short)f2bf(b.y);
        v[6] = (short)f2bf(b.z); v[7] = (short)f2bf(b.w);
        xf[ks] = v;
    }
    float s = rsd[rowc];
    #pragma unroll
    for (int nt = 0; nt < 8; ++nt) {
        f32x4 acc = {0.f, 0.f, 0.f, 0.f};
        #pragma unroll
        for (int ks = 0; ks < 4; ++ks) {
            int n = nt * 16 + lm;
            int g = ks * 4 + lk;
            bf16x8 wf = WL[n * 16 + (g ^ (n & 7))];
            acc = __builtin_amdgcn_mfma_f32_16x16x32_bf16(wf, xf[ks], acc, 0, 0, 0);
        }
        if (row < M) {
            unsigned int lo = (unsigned int)f2bf(acc[0] * s) |
                              ((unsigned int)f2bf(acc[1] * s) << 16);
            unsigned int hi = (unsigned int)f2bf(acc[2] * s) |
                              ((unsigned int)f2bf(acc[3] * s) << 16);
            uint2* yp = (uint2*)(Y2 + (size_t)row * IN_DIM + nt * 16 + lk * 4);
            *yp = make_uint2(lo, hi);
        }
    }
}

// One wave per node (round-4 structure, best measured), CSR bucket. Lane l:
// dims 8a..8a+7 (a=l&15), edge sub-slot grp=l>>4. Per 16-edge batch: one
// broadcast uint4 bucket read + 4 dwordx4 gathers; tails pre-padded with the
// dummy row index -> mask-free hot loop. rowinfo gives (base,deg) in one
// dwordx2 load.
__global__ __launch_bounds__(256) void k_agg(const uint4* __restrict__ Y4,
                                             const int* __restrict__ bucket,
                                             const int2* __restrict__ rowinfo,
                                             float* __restrict__ out, int n_n) {
    int gw = (int)((blockIdx.x * 256u + threadIdx.x) >> 6);
    int lane = threadIdx.x & 63;
    if (gw >= n_n) return;
    int2 ri = rowinfo[gw];
    int d = ri.y;
    int nb = (d + 15) >> 4;                 // 16-edge batches (>=1 since d>=1)
    const uint4* bk4 = (const uint4*)(bucket + ri.x);
    int grp = lane >> 4, a = lane & 15;
    f32x2 a0 = {0.f, 0.f}, a1 = {0.f, 0.f}, a2 = {0.f, 0.f}, a3 = {0.f, 0.f};

    uint4 tv = bk4[grp];
    for (int b = 0; b < nb; ++b) {
        int bn = (b + 1 < nb) ? b + 1 : b;
        uint4 tvn = bk4[bn * 4 + grp];      // prefetch next batch's targets
        uint4 v0 = Y4[(size_t)tv.x * 16 + a];
        uint4 v1 = Y4[(size_t)tv.y * 16 + a];
        uint4 v2 = Y4[(size_t)tv.z * 16 + a];
        uint4 v3 = Y4[(size_t)tv.w * 16 + a];
        #define ACCUM(V)                                                      \
        {                                                                     \
            f32x2 x;                                                          \
            x[0] = __uint_as_float((V).x << 16);                              \
            x[1] = __uint_as_float((V).x & 0xffff0000u);                      \
            asm("v_pk_add_f32 %0, %1, %0" : "+v"(a0) : "v"(x));               \
            x[0] = __uint_as_float((V).y << 16);                              \
            x[1] = __uint_as_float((V).y & 0xffff0000u);                      \
            asm("v_pk_add_f32 %0, %1, %0" : "+v"(a1) : "v"(x));               \
            x[0] = __uint_as_float((V).z << 16);                              \
            x[1] = __uint_as_float((V).z & 0xffff0000u);                      \
            asm("v_pk_add_f32 %0, %1, %0" : "+v"(a2) : "v"(x));               \
            x[0] = __uint_as_float((V).w << 16);                              \
            x[1] = __uint_as_float((V).w & 0xffff0000u);                      \
            asm("v_pk_add_f32 %0, %1, %0" : "+v"(a3) : "v"(x));               \
        }
        ACCUM(v0) ACCUM(v1) ACCUM(v2) ACCUM(v3)
        #undef ACCUM
        tv = tvn;
    }
    // Merge the 4 edge sub-slot groups (lanes a, a+16, a+32, a+48).
    #define MERGE(A)                                                          \
    {                                                                         \
        A[0] += __shfl_xor(A[0], 16); A[1] += __shfl_xor(A[1], 16);           \
        A[0] += __shfl_xor(A[0], 32); A[1] += __shfl_xor(A[1], 32);           \
    }
    MERGE(a0) MERGE(a1) MERGE(a2) MERGE(a3)
    #undef MERGE
    if (lane < 16) {
        float s = d > 0 ? rsqrtf((float)d) : 0.0f;
        float4 o0 = make_float4(fmaxf(a0[0] * s, 0.f), fmaxf(a0[1] * s, 0.f),
                                fmaxf(a1[0] * s, 0.f), fmaxf(a1[1] * s, 0.f));
        float4 o1 = make_float4(fmaxf(a2[0] * s, 0.f), fmaxf(a2[1] * s, 0.f),
                                fmaxf(a3[0] * s, 0.f), fmaxf(a3[1] * s, 0.f));
        float4* op = (float4*)(out + (size_t)gw * IN_DIM + a * 8);
        op[0] = o0;
        op[1] = o1;
    }
}

extern "C" void kernel_launch(void* const* d_in, const int* in_sizes, int n_in,
                              void* d_out, int out_size, void* d_ws, size_t ws_size,
                              hipStream_t stream) {
    const float* X = (const float*)d_in[0];
    const int* edges = (const int*)d_in[1];
    const float* W = (const float*)d_in[2];
    int n_n = in_sizes[0] / IN_DIM;
    int n_e = in_sizes[1] / 2;
    int nbins = (n_n + BIN_NODES - 1) >> NODE_SHIFT;   // 391 for n_n=100000

    char* ws = (char*)d_ws;
    size_t o = 0;
    auto take = [&](size_t bytes) -> char* {
        char* p = ws + o;
        o += (bytes + 511) & ~(size_t)511;
        return p;
    };
    float* rsd = (float*)take((size_t)n_n * 4);                       // 400 KB
    int2* rowinfo = (int2*)take((size_t)n_n * 8);                     // 800 KB
    int* bucket = (int*)take((size_t)nbins * BINCAP_E * 4);           // 16.0 MB
    // pairs (19.2 MB) aliases Y2's slot: consumed by k_binscatter before
    // k_mfma writes Y2. Y2 has n_n+1 rows; row n_n is the zeroed dummy row
    // (offset 25.6 MB, beyond the pairs region -> no clash).
    size_t y2_bytes = (size_t)(n_n + 1) * IN_DIM * 2;                 // 25.6 MB
    size_t pair_bytes = (size_t)nbins * BCAP * 8;                     // 19.2 MB
    char* big = take(y2_bytes > pair_bytes ? y2_bytes : pair_bytes);
    unsigned short* Y2 = (unsigned short*)big;
    unsigned long long* pairs = (unsigned long long*)big;
    int* bincur = (int*)take((size_t)nbins * 4);
    bf16x8* Wsw = (bf16x8*)take(2048 * 16);                           // 32 KB

    int nslab = (n_n + 15) / 16;
    k_prep<<<8, 256, 0, stream>>>(W, Wsw, bincur, nbins,
                                  (unsigned int*)(Y2 + (size_t)n_n * IN_DIM));
    k_partition<<<(n_e + CHUNK - 1) / CHUNK, 256, 0, stream>>>(edges, n_e, nbins, pairs, bincur);
    k_binscatter<<<nbins, 256, 0, stream>>>(pairs, bincur, bucket, rowinfo, rsd, n_n);
    k_mfma<<<(nslab + 3) / 4, 256, 0, stream>>>(X, Wsw, rsd, Y2, n_n);
    k_agg<<<(n_n + 3) / 4, 256, 0, stream>>>((const uint4*)Y2, bucket, rowinfo,
                                             (float*)d_out, n_n);
}

// Round 8
// 119.169 us; speedup vs baseline: 1.1632x; 1.0676x over previous
//
#include <hip/hip_runtime.h>

#define IN_DIM 128
#define CAP 64          // per-node degree cap; dataset max degree ~ 1+Poisson(15) << 64
#define NODE_SHIFT 8    // 256 nodes per coarse bin
#define BIN_NODES 256   // == blockDim of binscatter role
#define NB_MAX 512      // supports n_n up to 131072 (17-bit node ids in packed pairs)
#define BCAP 5120       // pairs per bin; mean ~4096, sigma ~62 -> 16 sigma slack
#define BINCAP_E 10240  // bucket entries per bin (padded CSR region), mean ~5900
#define CHUNK 4096      // edges per partition block (32KB LDS staging)

typedef __attribute__((ext_vector_type(8))) short bf16x8;
typedef __attribute__((ext_vector_type(4))) float f32x4;
typedef __attribute__((ext_vector_type(2))) float f32x2;

__device__ __forceinline__ unsigned short f2bf(float f) {
    unsigned int u = __float_as_uint(f);
    u += 0x7FFFu + ((u >> 16) & 1u);   // round-to-nearest-even
    return (unsigned short)(u >> 16);
}

// Fused prep: zero bincur, zero dummy Y2 row, rsd[n_n]=0 (dummy-target scale),
// convert W to swizzled bf16 granules: (n, g) -> Wsw[n*16 + (g ^ (n&7))].
__global__ void k_prep(const float* __restrict__ W, bf16x8* __restrict__ Wsw,
                       int* __restrict__ bincur, int nbins,
                       unsigned int* __restrict__ dummy, float* __restrict__ rsd,
                       int n_n) {
    int gi = blockIdx.x * 256 + threadIdx.x;
    if (gi < nbins) bincur[gi] = 0;
    if (gi < 64) dummy[gi] = 0;
    if (gi == 64) rsd[n_n] = 0.0f;
    if (gi >= 2048) return;
    int n = gi >> 4, g = gi & 15;
    const float* wp = W + n * IN_DIM + g * 8;
    float4 a = *(const float4*)wp;
    float4 b = *(const float4*)(wp + 4);
    bf16x8 v;
    v[0] = (short)f2bf(a.x); v[1] = (short)f2bf(a.y);
    v[2] = (short)f2bf(a.z); v[3] = (short)f2bf(a.w);
    v[4] = (short)f2bf(b.x); v[5] = (short)f2bf(b.y);
    v[6] = (short)f2bf(b.z); v[7] = (short)f2bf(b.w);
    Wsw[n * 16 + (g ^ (n & 7))] = v;
}

// Pass 1: partition edges into coarse bins of 256 head-nodes each.
// Output pairs packed into u32: (h & 255) << 17 | t   (t, n_n <= 131071).
__global__ __launch_bounds__(256) void k_partition(const int* __restrict__ edges, int n_e,
                                                   int nbins,
                                                   unsigned int* __restrict__ pairs,
                                                   int* __restrict__ bincur) {
    __shared__ unsigned long long sp[CHUNK];   // 32 KB staged (h<<17)|t
    __shared__ int hist[NB_MAX];
    __shared__ int base[NB_MAX];
    int tid = threadIdx.x;
    int e0 = blockIdx.x * CHUNK;
    int nloc = n_e - e0;
    if (nloc > CHUNK) nloc = CHUNK;
    for (int i = tid; i < nbins; i += 256) hist[i] = 0;
    __syncthreads();
    for (int i = tid; i < nloc; i += 256) {
        int h = edges[e0 + i];
        int t = edges[n_e + e0 + i];
        sp[i] = ((unsigned long long)(unsigned int)h << 17) | (unsigned int)t;
        atomicAdd(&hist[h >> NODE_SHIFT], 1);
    }
    __syncthreads();
    for (int b = tid; b < nbins; b += 256) {
        int c = hist[b];
        base[b] = c ? atomicAdd(&bincur[b], c) : 0;
        hist[b] = 0;
    }
    __syncthreads();
    for (int i = tid; i < nloc; i += 256) {
        unsigned long long p = sp[i];
        int b = (int)(p >> (17 + NODE_SHIFT));
        int pos = atomicAdd(&hist[b], 1);
        int g = base[b] + pos;
        if (g < BCAP) pairs[(size_t)b * BCAP + g] = (unsigned int)(p & 0x1FFFFFFu);
    }
}

// Heterogeneous fused kernel: blocks [0, nbins) run the binscatter role
// (LDS-staged pairs, per-node count -> scan -> padded-CSR scatter, emits
// rowinfo + rsd); blocks [nbins, nbins+nmf) run the UNSCALED bf16-MFMA GEMM
// Y2[m,:] = bf16(X[m,:] @ W^T). The two roles touch disjoint buffers, so the
// latency-bound scatter hides under the memory-bound GEMM.
__global__ __launch_bounds__(256) void k_binmfma(const unsigned int* __restrict__ pairs,
                                                 const int* __restrict__ bincur,
                                                 int* __restrict__ bucket,
                                                 int2* __restrict__ rowinfo,
                                                 float* __restrict__ rsd,
                                                 const float* __restrict__ X,
                                                 const bf16x8* __restrict__ Wg,
                                                 unsigned short* __restrict__ Y2,
                                                 int n_n, int nbins) {
    __shared__ union {
        struct {
            unsigned int sp[BCAP];                  // 20 KB staged packed pairs
            int lcur[BIN_NODES];
            int sbase[BIN_NODES];
            int wsum[4];
        } bs;
        bf16x8 wl[2048];                            // 32 KB swizzled bf16 W
    } u;
    int tid = threadIdx.x;

    if ((int)blockIdx.x < nbins) {
        // ---------------- binscatter role ----------------
        int b = blockIdx.x;
        u.bs.lcur[tid] = 0;
        __syncthreads();
        int n = bincur[b];
        if (n > BCAP) n = BCAP;
        const unsigned int* pp = pairs + (size_t)b * BCAP;
        for (int i = tid; i < n; i += 256) {
            unsigned int p = pp[i];
            u.bs.sp[i] = p;
            atomicAdd(&u.bs.lcur[p >> 17], 1);
        }
        __syncthreads();
        int draw = u.bs.lcur[tid];
        int dcap = draw < CAP ? draw : CAP;
        int v = (dcap + 15) & ~15;          // padded degree (multiple of 16)
        int lane = tid & 63, w = tid >> 6;
        int x = v;
        #pragma unroll
        for (int off = 1; off < 64; off <<= 1) {
            int y = __shfl_up(x, off);
            if (lane >= off) x += y;
        }
        if (lane == 63) u.bs.wsum[w] = x;
        __syncthreads();
        int wo = 0;
        for (int k = 0; k < w; ++k) wo += u.bs.wsum[k];
        int mybase = wo + x - v;            // intra-bin exclusive prefix
        u.bs.sbase[tid] = mybase;
        u.bs.lcur[tid] = 0;
        __syncthreads();
        int gbase = b * BINCAP_E;
        for (int i = tid; i < n; i += 256) {
            unsigned int p = u.bs.sp[i];
            int li = p >> 17;
            int t = p & 0x1FFFF;
            int pos = atomicAdd(&u.bs.lcur[li], 1);
            if (pos < CAP) {
                int idx = u.bs.sbase[li] + pos;
                if (idx < BINCAP_E) bucket[gbase + idx] = t;
            }
        }
        __syncthreads();
        int h = (b << NODE_SHIFT) + tid;
        if (h < n_n) {
            for (int s = dcap; s < v; ++s) {
                int idx = mybase + s;
                if (idx < BINCAP_E) bucket[gbase + idx] = n_n;   // dummy row pad
            }
            rowinfo[h] = make_int2(gbase + mybase, dcap);
            rsd[h] = draw > 0 ? rsqrtf((float)draw) : 0.0f;
        }
    } else {
        // ---------------- mfma (unscaled GEMM) role ----------------
        int M = n_n;
        int mb = blockIdx.x - nbins;
        for (int i = tid; i < 2048; i += 256) u.wl[i] = Wg[i];
        __syncthreads();
        int slab = mb * 4 + (tid >> 6);
        int m0 = slab * 16;
        if (m0 >= M) return;
        int l = tid & 63;
        int lm = l & 15, lk = l >> 4;
        int row = m0 + lm;
        int rowc = row < M ? row : M - 1;
        bf16x8 xf[4];
        const float* xbase = X + (size_t)rowc * IN_DIM + lk * 8;
        #pragma unroll
        for (int ks = 0; ks < 4; ++ks) {
            float4 a = *(const float4*)(xbase + ks * 32);
            float4 b2 = *(const float4*)(xbase + ks * 32 + 4);
            bf16x8 v;
            v[0] = (short)f2bf(a.x); v[1] = (short)f2bf(a.y);
            v[2] = (short)f2bf(a.z); v[3] = (short)f2bf(a.w);
            v[4] = (short)f2bf(b2.x); v[5] = (short)f2bf(b2.y);
            v[6] = (short)f2bf(b2.z); v[7] = (short)f2bf(b2.w);
            xf[ks] = v;
        }
        #pragma unroll
        for (int nt = 0; nt < 8; ++nt) {
            f32x4 acc = {0.f, 0.f, 0.f, 0.f};
            #pragma unroll
            for (int ks = 0; ks < 4; ++ks) {
                int nn = nt * 16 + lm;
                int g = ks * 4 + lk;
                bf16x8 wf = u.wl[nn * 16 + (g ^ (nn & 7))];
                acc = __builtin_amdgcn_mfma_f32_16x16x32_bf16(wf, xf[ks], acc, 0, 0, 0);
            }
            if (row < M) {
                unsigned int lo = (unsigned int)f2bf(acc[0]) |
                                  ((unsigned int)f2bf(acc[1]) << 16);
                unsigned int hi = (unsigned int)f2bf(acc[2]) |
                                  ((unsigned int)f2bf(acc[3]) << 16);
                uint2* yp = (uint2*)(Y2 + (size_t)row * IN_DIM + nt * 16 + lk * 4);
                *yp = make_uint2(lo, hi);
            }
        }
    }
}

// One wave per node, CSR bucket. Lane l: dims 8a..8a+7 (a=l&15), edge
// sub-slot grp=l>>4. Per 16-edge batch: one broadcast uint4 bucket read,
// 4 broadcast rsd[t] loads, 4 dwordx4 gathers; accumulate rsd[t]*y via
// v_pk_fma_f32. Tails pre-padded with dummy row (Y2[n_n]=0, rsd[n_n]=0).
__global__ __launch_bounds__(256) void k_agg(const uint4* __restrict__ Y4,
                                             const int* __restrict__ bucket,
                                             const int2* __restrict__ rowinfo,
                                             const float* __restrict__ rsd,
                                             float* __restrict__ out, int n_n) {
    int gw = (int)((blockIdx.x * 256u + threadIdx.x) >> 6);
    int lane = threadIdx.x & 63;
    if (gw >= n_n) return;
    int2 ri = rowinfo[gw];
    int d = ri.y;
    int nb = (d + 15) >> 4;                 // 16-edge batches (>=1 since d>=1)
    const uint4* bk4 = (const uint4*)(bucket + ri.x);
    int grp = lane >> 4, a = lane & 15;
    f32x2 a0 = {0.f, 0.f}, a1 = {0.f, 0.f}, a2 = {0.f, 0.f}, a3 = {0.f, 0.f};

    uint4 tv = bk4[grp];
    for (int b = 0; b < nb; ++b) {
        int bn = (b + 1 < nb) ? b + 1 : b;
        uint4 tvn = bk4[bn * 4 + grp];      // prefetch next batch's targets
        float s0 = rsd[tv.x], s1 = rsd[tv.y], s2 = rsd[tv.z], s3 = rsd[tv.w];
        uint4 v0 = Y4[(size_t)tv.x * 16 + a];
        uint4 v1 = Y4[(size_t)tv.y * 16 + a];
        uint4 v2 = Y4[(size_t)tv.z * 16 + a];
        uint4 v3 = Y4[(size_t)tv.w * 16 + a];
        #define ACCUM(V, S)                                                   \
        {                                                                     \
            f32x2 sv; sv[0] = (S); sv[1] = (S);                               \
            f32x2 x;                                                          \
            x[0] = __uint_as_float((V).x << 16);                              \
            x[1] = __uint_as_float((V).x & 0xffff0000u);                      \
            asm("v_pk_fma_f32 %0, %1, %2, %0" : "+v"(a0) : "v"(x), "v"(sv));  \
            x[0] = __uint_as_float((V).y << 16);                              \
            x[1] = __uint_as_float((V).y & 0xffff0000u);                      \
            asm("v_pk_fma_f32 %0, %1, %2, %0" : "+v"(a1) : "v"(x), "v"(sv));  \
            x[0] = __uint_as_float((V).z << 16);                              \
            x[1] = __uint_as_float((V).z & 0xffff0000u);                      \
            asm("v_pk_fma_f32 %0, %1, %2, %0" : "+v"(a2) : "v"(x), "v"(sv));  \
            x[0] = __uint_as_float((V).w << 16);                              \
            x[1] = __uint_as_float((V).w & 0xffff0000u);                      \
            asm("v_pk_fma_f32 %0, %1, %2, %0" : "+v"(a3) : "v"(x), "v"(sv));  \
        }
        ACCUM(v0, s0) ACCUM(v1, s1) ACCUM(v2, s2) ACCUM(v3, s3)
        #undef ACCUM
        tv = tvn;
    }
    // Merge the 4 edge sub-slot groups (lanes a, a+16, a+32, a+48).
    #define MERGE(A)                                                          \
    {                                                                         \
        A[0] += __shfl_xor(A[0], 16); A[1] += __shfl_xor(A[1], 16);           \
        A[0] += __shfl_xor(A[0], 32); A[1] += __shfl_xor(A[1], 32);           \
    }
    MERGE(a0) MERGE(a1) MERGE(a2) MERGE(a3)
    #undef MERGE
    if (lane < 16) {
        float s = rsd[gw];                  // true (uncapped) degree scale
        float4 o0 = make_float4(fmaxf(a0[0] * s, 0.f), fmaxf(a0[1] * s, 0.f),
                                fmaxf(a1[0] * s, 0.f), fmaxf(a1[1] * s, 0.f));
        float4 o1 = make_float4(fmaxf(a2[0] * s, 0.f), fmaxf(a2[1] * s, 0.f),
                                fmaxf(a3[0] * s, 0.f), fmaxf(a3[1] * s, 0.f));
        float4* op = (float4*)(out + (size_t)gw * IN_DIM + a * 8);
        op[0] = o0;
        op[1] = o1;
    }
}

extern "C" void kernel_launch(void* const* d_in, const int* in_sizes, int n_in,
                              void* d_out, int out_size, void* d_ws, size_t ws_size,
                              hipStream_t stream) {
    const float* X = (const float*)d_in[0];
    const int* edges = (const int*)d_in[1];
    const float* W = (const float*)d_in[2];
    int n_n = in_sizes[0] / IN_DIM;
    int n_e = in_sizes[1] / 2;
    int nbins = (n_n + BIN_NODES - 1) >> NODE_SHIFT;   // 391 for n_n=100000

    char* ws = (char*)d_ws;
    size_t o = 0;
    auto take = [&](size_t bytes) -> char* {
        char* p = ws + o;
        o += (bytes + 511) & ~(size_t)511;
        return p;
    };
    float* rsd = (float*)take((size_t)(n_n + 1) * 4);                 // 400 KB
    int2* rowinfo = (int2*)take((size_t)n_n * 8);                     // 800 KB
    int* bucket = (int*)take((size_t)nbins * BINCAP_E * 4);           // 16.0 MB
    unsigned short* Y2 = (unsigned short*)take((size_t)(n_n + 1) * IN_DIM * 2); // 25.6 MB
    unsigned int* pairs = (unsigned int*)take((size_t)nbins * BCAP * 4);        // 8.0 MB
    int* bincur = (int*)take((size_t)nbins * 4);
    bf16x8* Wsw = (bf16x8*)take(2048 * 16);                           // 32 KB

    int nslab = (n_n + 15) / 16;
    int nmf = (nslab + 3) / 4;
    k_prep<<<8, 256, 0, stream>>>(W, Wsw, bincur, nbins,
                                  (unsigned int*)(Y2 + (size_t)n_n * IN_DIM), rsd, n_n);
    k_partition<<<(n_e + CHUNK - 1) / CHUNK, 256, 0, stream>>>(edges, n_e, nbins, pairs, bincur);
    k_binmfma<<<nbins + nmf, 256, 0, stream>>>(pairs, bincur, bucket, rowinfo, rsd,
                                               X, Wsw, Y2, n_n, nbins);
    k_agg<<<(n_n + 3) / 4, 256, 0, stream>>>((const uint4*)Y2, bucket, rowinfo, rsd,
                                             (float*)d_out, n_n);
}